// Round 2
// baseline (1070.450 us; speedup 1.0000x reference)
//
#include <hip/hip_runtime.h>
#include <hip/hip_cooperative_groups.h>
#include <stdint.h>

namespace cg = cooperative_groups;

// PDP soft-mask pruning, 8192x8192 f32. Single cooperative kernel:
// sample-hist -> bracket -> compact+count -> low16-refine -> mask,
// with 4 grid syncs replacing the previous 9-dispatch serial chain.

typedef float floatx4 __attribute__((ext_vector_type(4)));  // for nontemporal store

constexpr int NB = 1024;                 // 4 blocks/CU x 256 CUs (co-resident)
constexpr int NT = 256;
constexpr long long GSZ = (long long)NB * NT;
constexpr unsigned CAND_CAP = 1u << 22;  // 4M candidate slots (16 MB)
constexpr int LCAP = 8192;               // per-block candidate staging
constexpr int BRW = 1024;                // max bracket width (bins)
constexpr long long CMARG = 8192;        // sample rank margin (DKW: fail < 2e-111)

// ws layout (bytes):
//       0  hist_s   32768 u32   (15-bit sample histogram)
//  131072  h2a      65536 u32   (low-16 hist, bin b0)
//  393216  h2b      65536 u32   (low-16 hist, bin b1)
//  655360  h2ac       256 u32   (coarse of h2a)
//  656384  h2bc       256 u32   (coarse of h2b)
//  657408  chistB    1024 u32   (bracket-bin counts, full data)
//  661504  above    u64
//  661512  cand_cnt u32
// 1048576  cand     4M u32
constexpr long long ZWORDS = 661520 / 4;

__global__ __launch_bounds__(NT, 4) void k_pdp(const float4* __restrict__ w4,
                                               float4* __restrict__ o4,
                                               uint8_t* __restrict__ ws,
                                               long long n4, long long k0, long long k1)
{
    unsigned* hist_s = (unsigned*)(ws);
    unsigned* h2a    = (unsigned*)(ws + 131072);
    unsigned* h2b    = (unsigned*)(ws + 393216);
    unsigned* h2ac   = (unsigned*)(ws + 655360);
    unsigned* h2bc   = (unsigned*)(ws + 656384);
    unsigned* chistB = (unsigned*)(ws + 657408);
    unsigned long long* above = (unsigned long long*)(ws + 661504);
    unsigned* cand_cnt = (unsigned*)(ws + 661512);
    unsigned* cand   = (unsigned*)(ws + 1048576);
    unsigned* zbase  = (unsigned*)(ws);

    // 36,896 B: 4 blocks/CU x 36.9 KB = 147.6 KB <= 160 KB LDS/CU
    __shared__ unsigned sh[9224];

    cg::grid_group grid = cg::this_grid();
    const int tid = threadIdx.x;
    const int bid = blockIdx.x;
    const long long gtid = (long long)bid * NT + tid;

    // ---------------- P0: zero accumulators (replaces hipMemsetAsync) ------
    for (long long i = gtid; i < ZWORDS; i += GSZ) zbase[i] = 0u;
    grid.sync();                                                    // S1

    // ---------------- P1: sample histogram (1024 contiguous floats/block) --
    for (int i = tid; i < 8192; i += NT) sh[i] = 0u;
    __syncthreads();
    {
        const long long base4 = (long long)bid * (n4 >> 10);
        const long long idx = base4 + tid;
        if (idx < n4) {
            float4 v = w4[idx];
            float f[4] = {v.x, v.y, v.z, v.w};
            #pragma unroll
            for (int c = 0; c < 4; c++) {
                unsigned bin = __float_as_uint(fabsf(f[c])) >> 16;
                if (bin < 16384)
                    atomicAdd(&sh[bin >> 1], 1u << ((bin & 1) * 16)); // |w|<2.0 path
                else
                    atomicAdd(&hist_s[bin], 1u);                      // overflow path
            }
        }
    }
    __syncthreads();
    for (int i = tid; i < 8192; i += NT) {
        unsigned v = sh[i];
        if (v) {
            unsigned lo = v & 0xFFFFu, hi = v >> 16;
            if (lo) atomicAdd(&hist_s[2 * i],     lo);
            if (hi) atomicAdd(&hist_s[2 * i + 1], hi);
        }
    }
    grid.sync();                                                    // S2

    // ---------------- P2': per-block redundant scan -> BH, BL --------------
    unsigned BH, BL;
    {
        const int base = tid * 128;
        unsigned psum = 0;
        for (int j = 0; j < 128; j++) psum += hist_s[base + j];
        sh[tid] = psum;
        __syncthreads();
        if (tid == 0) {   // suffix over 256 partials (higher bins = higher t)
            unsigned acc = 0;
            for (int t = NT - 1; t >= 0; t--) { sh[256 + t] = acc; acc += sh[t]; }
            sh[516] = acc;                       // total samples actually taken
        }
        __syncthreads();
        const unsigned total = sh[516];
        long long rhi = (long long)(total / 2) - CMARG; if (rhi < 0) rhi = 0;
        long long rlo = (long long)(total / 2) + CMARG;
        if (rlo > (long long)total - 1) rlo = (long long)total - 1;
        unsigned long long cum = sh[256 + tid];
        for (int j = 127; j >= 0; j--) {         // descending within chunk
            unsigned bin = (unsigned)(base + j);
            unsigned cnt = hist_s[bin];
            if (cnt) {
                if ((unsigned long long)rhi >= cum && (unsigned long long)rhi < cum + cnt) sh[517] = bin; // BH
                if ((unsigned long long)rlo >= cum && (unsigned long long)rlo < cum + cnt) sh[518] = bin; // BL
                cum += cnt;
            }
        }
        __syncthreads();
        BH = sh[517]; BL = sh[518];
        if (BH - BL >= (unsigned)BRW) BL = BH - (BRW - 1);  // pathological clamp
        __syncthreads();   // before sh reuse
    }

    // ---------------- P3: full pass — above count + compact + bin counts ---
    {
        unsigned* lbuf = sh;            // [0..8191]
        unsigned* binc = sh + 8192;     // [0..1023]
        for (int i = tid; i < 1024; i += NT) binc[i] = 0u;
        if (tid == 0) sh[9216] = 0u;    // lcnt
        __syncthreads();
        unsigned my_above = 0;
        #pragma unroll 2
        for (long long i = gtid; i < n4; i += GSZ) {
            float4 v = w4[i];
            float f[4] = {v.x, v.y, v.z, v.w};
            #pragma unroll
            for (int c = 0; c < 4; c++) {
                unsigned bits = __float_as_uint(fabsf(f[c]));
                unsigned bin = bits >> 16;
                my_above += (bin > BH) ? 1u : 0u;
                if (bin >= BL && bin <= BH) {
                    unsigned p = atomicAdd(&sh[9216], 1u);
                    if (p < (unsigned)LCAP) lbuf[p] = bits;
                    atomicAdd(&binc[bin - BL], 1u);
                }
            }
        }
        #pragma unroll
        for (int off = 32; off > 0; off >>= 1)
            my_above += __shfl_down(my_above, off, 64);
        if ((tid & 63) == 0 && my_above)
            atomicAdd(above, (unsigned long long)my_above);
        __syncthreads();
        for (int i = tid; i < 1024; i += NT) {
            unsigned c0 = binc[i];
            if (c0) atomicAdd(&chistB[i], c0);
        }
        const unsigned lc = sh[9216] < (unsigned)LCAP ? sh[9216] : (unsigned)LCAP;
        if (tid == 0) sh[9217] = atomicAdd(cand_cnt, lc);
        __syncthreads();
        const unsigned gb = sh[9217];
        for (unsigned i = tid; i < lc; i += NT) {
            unsigned dst = gb + i;
            if (dst < CAND_CAP) cand[dst] = lbuf[i];
        }
    }
    grid.sync();                                                    // S3

    // ---------------- P5': resolve exact bins b0,b1 + within-bin ranks -----
    unsigned b0, r0, b1, r1, candN;
    if (tid == 0) {
        unsigned long long A = *above;
        unsigned long long k0p = (unsigned long long)(k0 - (long long)A);
        unsigned long long k1p = (unsigned long long)(k1 - (long long)A);
        unsigned long long cum = 0;
        unsigned bb0 = BL, rr0 = 0, bb1 = BL, rr1 = 0;
        for (int b = (int)BH; b >= (int)BL; b--) {   // W ~ 5 bins in practice
            unsigned cnt = chistB[b - (int)BL];
            if (cnt) {
                if (k0p >= cum && k0p < cum + cnt) { bb0 = (unsigned)b; rr0 = (unsigned)(k0p - cum); }
                if (k1p >= cum && k1p < cum + cnt) { bb1 = (unsigned)b; rr1 = (unsigned)(k1p - cum); }
                cum += cnt;
            }
        }
        sh[9218] = bb0; sh[9219] = rr0; sh[9220] = bb1; sh[9221] = rr1;
        unsigned cc = *cand_cnt;
        sh[9222] = cc < CAND_CAP ? cc : CAND_CAP;
    }
    __syncthreads();
    b0 = sh[9218]; r0 = sh[9219]; b1 = sh[9220]; r1 = sh[9221]; candN = sh[9222];
    __syncthreads();

    // ---------------- P6: low-16 histograms (fine + 256-entry coarse) ------
    for (int i = tid; i < 512; i += NT) sh[i] = 0u;
    __syncthreads();
    for (long long i = gtid; i < (long long)candN; i += GSZ) {
        unsigned bits = cand[i];
        unsigned hi = bits >> 16, lo = bits & 0xFFFFu;
        if (hi == b0)      { atomicAdd(&h2a[lo], 1u); atomicAdd(&sh[lo >> 8], 1u); }
        else if (hi == b1) { atomicAdd(&h2b[lo], 1u); atomicAdd(&sh[256 + (lo >> 8)], 1u); }
    }
    __syncthreads();
    {
        unsigned ca = sh[tid], cb = sh[256 + tid];
        if (ca) atomicAdd(&h2ac[tid], ca);
        if (cb) atomicAdd(&h2bc[tid], cb);
    }
    grid.sync();                                                    // S4

    // ---------------- P7': per-block redundant low-16 resolve -> t^2 -------
    auto resolve = [&](unsigned rank, const unsigned* fine, const unsigned* coarse) -> unsigned {
        __syncthreads();
        sh[tid] = coarse[tid];
        __syncthreads();
        if (tid == 0) {
            unsigned long long cum = 0; unsigned seg = 0, rem = 0;
            for (int s = 255; s >= 0; s--) {
                unsigned c0 = sh[s];
                if (c0) {
                    if ((unsigned long long)rank >= cum && (unsigned long long)rank < cum + c0) {
                        seg = (unsigned)s; rem = (unsigned)((unsigned long long)rank - cum);
                    }
                    cum += c0;
                }
            }
            sh[512] = seg; sh[513] = rem;
        }
        __syncthreads();
        const unsigned seg = sh[512], rem = sh[513];
        sh[tid] = fine[seg * 256 + tid];
        __syncthreads();
        if (tid == 0) {
            unsigned long long cum = 0; unsigned binlo = 0;
            for (int j = 255; j >= 0; j--) {
                unsigned c0 = sh[j];
                if (c0) {
                    if ((unsigned long long)rem >= cum && (unsigned long long)rem < cum + c0) binlo = (unsigned)j;
                    cum += c0;
                }
            }
            sh[514] = seg * 256 + binlo;
        }
        __syncthreads();
        return sh[514];
    };
    const unsigned lo0 = resolve(r0, h2a, h2ac);
    const unsigned lo1 = (b1 == b0) ? resolve(r1, h2a, h2ac) : resolve(r1, h2b, h2bc);
    const float v0 = __uint_as_float((b0 << 16) | lo0);
    const float v1 = __uint_as_float((b1 << 16) | lo1);
    const float th = 0.5f * (v0 + v1);
    const float tsq = th * th;

    // ---------------- P8: mask. Reverse traversal to harvest L3 residency --
    // (compact pass just streamed w through the 256 MiB L3; tail is freshest)
    floatx4* __restrict__ onat = (floatx4*)o4;
    #pragma unroll 2
    for (long long i = n4 - 1 - gtid; i >= 0; i -= GSZ) {
        float4 v = w4[i];
        floatx4 o;
        o.x = v.x / (1.0f + __expf((tsq - v.x * v.x) * 1e5f));
        o.y = v.y / (1.0f + __expf((tsq - v.y * v.y) * 1e5f));
        o.z = v.z / (1.0f + __expf((tsq - v.z * v.z) * 1e5f));
        o.w = v.w / (1.0f + __expf((tsq - v.w * v.w) * 1e5f));
        __builtin_nontemporal_store(o, &onat[i]);
    }
}

extern "C" void kernel_launch(void* const* d_in, const int* in_sizes, int n_in,
                              void* d_out, int out_size, void* d_ws, size_t ws_size,
                              hipStream_t stream) {
    const float4* w4 = (const float4*)d_in[0];
    float4* o4 = (float4*)d_out;
    const long long n  = (long long)in_sizes[0];
    long long n4 = n / 4;

    long long lim = n / 2;
    if (lim > n - 2) lim = n - 2;
    long long k0 = lim, k1 = lim + 1;

    uint8_t* ws = (uint8_t*)d_ws;

    void* args[] = { (void*)&w4, (void*)&o4, (void*)&ws,
                     (void*)&n4, (void*)&k0, (void*)&k1 };
    (void)hipLaunchCooperativeKernel((const void*)k_pdp, dim3(NB), dim3(NT),
                                     args, 0, stream);
}